// Round 6
// baseline (232.069 us; speedup 1.0000x reference)
//
#include <hip/hip_runtime.h>
#include <hip/hip_bf16.h>

typedef __bf16 bf16x8 __attribute__((ext_vector_type(8)));
typedef __bf16 bf16x4 __attribute__((ext_vector_type(4)));
typedef float fx4 __attribute__((ext_vector_type(4)));
typedef float fx16 __attribute__((ext_vector_type(16)));

#define AS1 __attribute__((address_space(1)))
#define AS3 __attribute__((address_space(3)))

// ---------------------------------------------------------------- cast x -> bf16
__global__ __launch_bounds__(256) void cast_x(const float4* __restrict__ X, __bf16* __restrict__ Xb) {
    int i = blockIdx.x * 256 + threadIdx.x;
    float4 v = X[i];
    bf16x4 o = { (__bf16)v.x, (__bf16)v.y, (__bf16)v.z, (__bf16)v.w };
    *(bf16x4*)(Xb + (size_t)i * 4) = o;
}

// ------------------------------------------------- all 4 weight transposes in one launch
__global__ __launch_bounds__(256) void transpose_all(const float* __restrict__ wq, const float* __restrict__ wk,
                                                     const float* __restrict__ wv, const float* __restrict__ wo,
                                                     __bf16* __restrict__ WqkvT, __bf16* __restrict__ WoT) {
    constexpr int K = 2048;
    __shared__ float t[32][33];
    const int bx = blockIdx.x;
    const float* W; __bf16* Wt; int N, n0;
    if (bx < 64)      { W = wq; Wt = WqkvT;                        N = 2048; n0 = bx * 32; }
    else if (bx < 80) { W = wk; Wt = WqkvT + (size_t)2048 * 2048;  N = 512;  n0 = (bx - 64) * 32; }
    else if (bx < 96) { W = wv; Wt = WqkvT + (size_t)2560 * 2048;  N = 512;  n0 = (bx - 80) * 32; }
    else              { W = wo; Wt = WoT;                          N = 2048; n0 = (bx - 96) * 32; }
    const int tx = threadIdx.x & 31, ty = threadIdx.x >> 5;
    const int k0 = blockIdx.y * 32;
#pragma unroll
    for (int i = 0; i < 4; ++i)
        t[ty + i * 8][tx] = W[(size_t)(k0 + ty + i * 8) * N + n0 + tx];
    __syncthreads();
#pragma unroll
    for (int i = 0; i < 4; ++i)
        Wt[(size_t)(n0 + ty + i * 8) * K + k0 + tx] = (__bf16)t[tx][ty + i * 8];
}

// ------------------------------------------------- QKV GEMM, BN=64 (one head per block), fused RoPE/split
__global__ __launch_bounds__(256) void gemm_qkv(const __bf16* __restrict__ A, const __bf16* __restrict__ Bt,
                                                __bf16* __restrict__ Qr, __bf16* __restrict__ Kr,
                                                __bf16* __restrict__ Vt) {
    constexpr int K = 2048;
    __shared__ __align__(16) __bf16 lA[128 * 32];
    __shared__ __align__(16) __bf16 lB[64 * 32];
    const int tid = threadIdx.x;
    const int wave = tid >> 6, lane = tid & 63;
    const int quad = lane >> 4, l16 = lane & 15;
    const int m0 = blockIdx.x * 128, n0 = blockIdx.y * 64;
    fx4 acc[2][4] = {};

    int cr[3], cc[3];
    const __bf16* csrc[3];
    __bf16* cdst[3];
#pragma unroll
    for (int it = 0; it < 3; ++it) {
        const int c = wave * 3 + it;
        if (c < 8) {
            const int boff = c * 1024 + lane * 16;
            cr[it] = boff >> 6; cc[it] = (boff & 63) >> 1;
            csrc[it] = A + (size_t)(m0 + cr[it]) * K;
            cdst[it] = lA + c * 512;
        } else {
            const int boff = (c - 8) * 1024 + lane * 16;
            cr[it] = boff >> 6; cc[it] = (boff & 63) >> 1;
            csrc[it] = Bt + (size_t)(n0 + cr[it]) * K;
            cdst[it] = lB + (c - 8) * 512;
        }
    }

    for (int k0 = 0; k0 < K; k0 += 32) {
        __syncthreads();
#pragma unroll
        for (int it = 0; it < 3; ++it)
            __builtin_amdgcn_global_load_lds((const AS1 void*)(csrc[it] + k0 + cc[it]),
                                             (AS3 void*)cdst[it], 16, 0, 0);
        __builtin_amdgcn_s_waitcnt(0);
        __syncthreads();

        bf16x8 af[2], bfr[4];
#pragma unroll
        for (int i = 0; i < 2; ++i) af[i] = *(const bf16x8*)&lA[(wave * 32 + i * 16 + l16) * 32 + quad * 8];
#pragma unroll
        for (int j = 0; j < 4; ++j) bfr[j] = *(const bf16x8*)&lB[(j * 16 + l16) * 32 + quad * 8];
#pragma unroll
        for (int i = 0; i < 2; ++i)
#pragma unroll
            for (int j = 0; j < 4; ++j)
                acc[i][j] = __builtin_amdgcn_mfma_f32_16x16x32_bf16(af[i], bfr[j], acc[i][j], 0, 0, 0);
    }

    const int by = blockIdx.y;
    if (by < 40) {
        const float scale = (by < 32) ? 0.18033688011112042f : 1.0f;   // Q: 0.125*log2(e)
        __bf16* base = (by < 32) ? (Qr + (size_t)by * 2048 * 64)
                                 : (Kr + (size_t)(by - 32) * 2048 * 64);
#pragma unroll
        for (int jj = 0; jj < 2; ++jj) {
            const int dlo = jj * 16 + l16;
            const float inv = __builtin_amdgcn_exp2f(-(float)dlo * 0.41524101186092029f);
#pragma unroll
            for (int i = 0; i < 2; ++i)
#pragma unroll
                for (int r = 0; r < 4; ++r) {
                    const int s = m0 + wave * 32 + i * 16 + quad * 4 + r;
                    float sn, cs;
                    __sincosf((float)s * inv, &sn, &cs);
                    const float lo = acc[i][jj][r], hv = acc[i][jj + 2][r];
                    base[(size_t)s * 64 + dlo]      = (__bf16)((lo * cs - hv * sn) * scale);
                    base[(size_t)s * 64 + dlo + 32] = (__bf16)((hv * cs + lo * sn) * scale);
                }
        }
    } else {
        __bf16* vb = Vt + (size_t)(by - 40) * 64 * 2048;
#pragma unroll
        for (int i = 0; i < 2; ++i)
#pragma unroll
            for (int j = 0; j < 4; ++j) {
                const int d = j * 16 + l16;
                const int s0 = m0 + wave * 32 + i * 16 + quad * 4;
                bf16x4 p;
#pragma unroll
                for (int r = 0; r < 4; ++r) p[r] = (__bf16)acc[i][j][r];
                *(bf16x4*)&vb[(size_t)d * 2048 + s0] = p;
            }
    }
}

// ------------------------------------------------- out-projection GEMM, split-K=2
__global__ __launch_bounds__(256) void gemm_bt_sk(const __bf16* __restrict__ A, const __bf16* __restrict__ Bt,
                                                  float* __restrict__ C0, float* __restrict__ C1,
                                                  int M, int N, int K) {
    __shared__ __align__(16) __bf16 lA[128 * 32];
    __shared__ __align__(16) __bf16 lB[128 * 32];
    const int tid = threadIdx.x;
    const int wave = tid >> 6, lane = tid & 63;
    const int quad = lane >> 4, l16 = lane & 15;
    const int m0 = blockIdx.x * 128, n0 = blockIdx.y * 128;
    const int kz = blockIdx.z;
    const int kbeg = kz * (K >> 1), kend = kbeg + (K >> 1);
    float* C = kz ? C1 : C0;
    const int wm = (wave >> 1) * 64, wn = (wave & 1) * 64;
    fx4 acc[4][4] = {};

    const int st0 = wave * 1024;
    const int st1 = 4096 + wave * 1024;
    const int r0 = (st0 + lane * 16) >> 6, c0 = ((st0 + lane * 16) & 63) >> 1;
    const int r1 = (st1 + lane * 16) >> 6, c1 = ((st1 + lane * 16) & 63) >> 1;

    for (int k0 = kbeg; k0 < kend; k0 += 32) {
        __syncthreads();
        __builtin_amdgcn_global_load_lds((const AS1 void*)(A + (size_t)(m0 + r0) * K + k0 + c0),
                                         (AS3 void*)(lA + (st0 >> 1)), 16, 0, 0);
        __builtin_amdgcn_global_load_lds((const AS1 void*)(A + (size_t)(m0 + r1) * K + k0 + c1),
                                         (AS3 void*)(lA + (st1 >> 1)), 16, 0, 0);
        __builtin_amdgcn_global_load_lds((const AS1 void*)(Bt + (size_t)(n0 + r0) * K + k0 + c0),
                                         (AS3 void*)(lB + (st0 >> 1)), 16, 0, 0);
        __builtin_amdgcn_global_load_lds((const AS1 void*)(Bt + (size_t)(n0 + r1) * K + k0 + c1),
                                         (AS3 void*)(lB + (st1 >> 1)), 16, 0, 0);
        __builtin_amdgcn_s_waitcnt(0);
        __syncthreads();

        bf16x8 af[4], bfr[4];
#pragma unroll
        for (int i = 0; i < 4; ++i) af[i] = *(const bf16x8*)&lA[(wm + i * 16 + l16) * 32 + quad * 8];
#pragma unroll
        for (int j = 0; j < 4; ++j) bfr[j] = *(const bf16x8*)&lB[(wn + j * 16 + l16) * 32 + quad * 8];
#pragma unroll
        for (int i = 0; i < 4; ++i)
#pragma unroll
            for (int j = 0; j < 4; ++j)
                acc[i][j] = __builtin_amdgcn_mfma_f32_16x16x32_bf16(af[i], bfr[j], acc[i][j], 0, 0, 0);
    }
#pragma unroll
    for (int i = 0; i < 4; ++i)
#pragma unroll
        for (int j = 0; j < 4; ++j) {
            const int row = m0 + wm + i * 16 + quad * 4;
            const int col = n0 + wn + j * 16 + l16;
#pragma unroll
            for (int r = 0; r < 4; ++r)
                C[(size_t)(row + r) * N + col] = acc[i][j][r];
        }
}

// ------------------------------------------------- out += partial (deterministic split-K reduce)
__global__ __launch_bounds__(256) void reduce_add(float4* __restrict__ out, const float4* __restrict__ p) {
    const int i = blockIdx.x * 256 + threadIdx.x;
    float4 a = out[i];
    const float4 b = p[i];
    a.x += b.x; a.y += b.y; a.z += b.z; a.w += b.w;
    out[i] = a;
}

// ------------------------------------------------- flash attention, 8 waves, split-K-in-block
// grid (16 q-tiles of 128, 32 heads), 512 thr = 8 waves. Waves 0-3 (grp 0) process even
// key-tiles, waves 4-7 (grp 1) odd key-tiles, each grp with private lK/lV buffers.
// Fixed-max softmax (p = exp2(s), Q pre-scaled) -> partials combine by plain adds
// through LDS at the end. 73.7 KB LDS -> 2 blocks/CU = 16 waves/CU.
// COMBINE ALIASING (R4 bugfix): lO (32 KB) lives in lP (36 KB), lL (512 B) in lK
// (18 KB) -- disjoint declared arrays, no overlap. R4 had lO spilling out of lK
// into lV where lL lived -> l_pair clobbered O partials (absmax 0.549).
__global__ __launch_bounds__(512, 4) void flash_attn(const __bf16* __restrict__ Qr, const __bf16* __restrict__ Kr,
                                                     const __bf16* __restrict__ Vt, __bf16* __restrict__ O) {
    constexpr int S = 2048;
    __shared__ __align__(16) __bf16 lK[2][64 * 72];   // [grp][key][d] stride 72 (18432 B)
    __shared__ __align__(16) __bf16 lV[2][64 * 72];   // [grp][d][key] stride 72 (18432 B)
    __shared__ __align__(16) __bf16 lP[8][32 * 72];   // per-wave [q][key] stride 72 (36864 B)
    const int qt = blockIdx.x, h = blockIdx.y, kvh = h >> 2;
    const int tid = threadIdx.x, wave = tid >> 6, lane = tid & 63;
    const int grp = wave >> 2, w4 = wave & 3;
    const int l32 = lane & 31, hi = lane >> 5;

    const int qrow = qt * 128 + w4 * 32 + l32;
    const __bf16* qptr = Qr + ((size_t)h * S + qrow) * 64;
    bf16x8 qf[4];
#pragma unroll
    for (int kc = 0; kc < 4; ++kc) qf[kc] = *(const bf16x8*)(qptr + kc * 16 + hi * 8);

    const __bf16* Kbase = Kr + (size_t)kvh * S * 64;
    const __bf16* Vbase = Vt + (size_t)kvh * 64 * S;

    const int gtid = tid & 255;               // index within group
    const int krow = gtid >> 3;               // 0..31
    const int kcol = (gtid & 7) * 8;

    // prefetch this group's first tile (kt = grp)
    bf16x8 kreg0 = *(const bf16x8*)(Kbase + (size_t)(grp * 64 + krow) * 64 + kcol);
    bf16x8 kreg1 = *(const bf16x8*)(Kbase + (size_t)(grp * 64 + 32 + krow) * 64 + kcol);
    bf16x8 vreg0 = *(const bf16x8*)(Vbase + (size_t)krow * S + grp * 64 + kcol);
    bf16x8 vreg1 = *(const bf16x8*)(Vbase + (size_t)(32 + krow) * S + grp * 64 + kcol);

    fx16 ov0, ov1;
#pragma unroll
    for (int i = 0; i < 16; ++i) { ov0[i] = 0.f; ov1[i] = 0.f; }
    float l_acc = 0.f;
    __bf16* lPw = &lP[wave][0];
    __bf16* lKg = &lK[grp][0];
    __bf16* lVg = &lV[grp][0];

    for (int it = 0; it < 16; ++it) {
        const int kt = it * 2 + grp;
        __syncthreads();
        *(bf16x8*)&lKg[krow * 72 + kcol] = kreg0;
        *(bf16x8*)&lKg[(32 + krow) * 72 + kcol] = kreg1;
        *(bf16x8*)&lVg[krow * 72 + kcol] = vreg0;
        *(bf16x8*)&lVg[(32 + krow) * 72 + kcol] = vreg1;
        const int ktn = (it + 1 < 16) ? kt + 2 : kt;
        kreg0 = *(const bf16x8*)(Kbase + (size_t)(ktn * 64 + krow) * 64 + kcol);
        kreg1 = *(const bf16x8*)(Kbase + (size_t)(ktn * 64 + 32 + krow) * 64 + kcol);
        vreg0 = *(const bf16x8*)(Vbase + (size_t)krow * S + ktn * 64 + kcol);
        vreg1 = *(const bf16x8*)(Vbase + (size_t)(32 + krow) * S + ktn * 64 + kcol);
        __syncthreads();

        // S^T = K . Q^T
        fx16 sc0, sc1;
#pragma unroll
        for (int i = 0; i < 16; ++i) { sc0[i] = 0.f; sc1[i] = 0.f; }
#pragma unroll
        for (int kc = 0; kc < 4; ++kc) {
            const bf16x8 a0 = *(const bf16x8*)&lKg[l32 * 72 + kc * 16 + hi * 8];
            const bf16x8 a1 = *(const bf16x8*)&lKg[(32 + l32) * 72 + kc * 16 + hi * 8];
            sc0 = __builtin_amdgcn_mfma_f32_32x32x16_bf16(a0, qf[kc], sc0, 0, 0, 0);
            sc1 = __builtin_amdgcn_mfma_f32_32x32x16_bf16(a1, qf[kc], sc1, 0, 0, 0);
        }

        // fixed-max softmax: p = exp2(s); key = mt*32 + (rg&3) + 8*(rg>>2) + 4*hi, q = l32
#pragma unroll
        for (int mt = 0; mt < 2; ++mt) {
#pragma unroll
            for (int rg2 = 0; rg2 < 4; ++rg2) {
                bf16x4 pk;
#pragma unroll
                for (int r = 0; r < 4; ++r) {
                    const float p = __builtin_amdgcn_exp2f(mt ? sc1[rg2 * 4 + r] : sc0[rg2 * 4 + r]);
                    l_acc += p;
                    pk[r] = (__bf16)p;
                }
                *(bf16x4*)&lPw[l32 * 72 + mt * 32 + rg2 * 8 + hi * 4] = pk;
            }
        }

        // O^T += V^T . P^T
#pragma unroll
        for (int kc = 0; kc < 4; ++kc) {
            const bf16x8 pb = *(const bf16x8*)&lPw[l32 * 72 + kc * 16 + hi * 8];
            const bf16x8 va0 = *(const bf16x8*)&lVg[l32 * 72 + kc * 16 + hi * 8];
            const bf16x8 va1 = *(const bf16x8*)&lVg[(32 + l32) * 72 + kc * 16 + hi * 8];
            ov0 = __builtin_amdgcn_mfma_f32_32x32x16_bf16(va0, pb, ov0, 0, 0, 0);
            ov1 = __builtin_amdgcn_mfma_f32_32x32x16_bf16(va1, pb, ov1, 0, 0, 0);
        }
    }

    // per-group l (this wave's half of the keys)
    const float l_pair = l_acc + __shfl_xor(l_acc, 32, 64);

    // cross-group combine through LDS. lO in lP (32768 <= 36864 B), lL in lK -- disjoint.
    fx4* lO = (fx4*)&lP[0][0];               // 32 slots x 64 lanes x 16 B
    float* lL = (float*)&lK[0][0];           // 128 floats
    __syncthreads();                         // all loop reads of lK/lV/lP done
    if (grp == 1) {
#pragma unroll
        for (int ic = 0; ic < 4; ++ic) {
            fx4 c0, c1;
#pragma unroll
            for (int r = 0; r < 4; ++r) { c0[r] = ov0[ic * 4 + r]; c1[r] = ov1[ic * 4 + r]; }
            lO[(ic * 4 + w4) * 64 + lane] = c0;
            lO[((ic + 4) * 4 + w4) * 64 + lane] = c1;
        }
        if (hi == 0) lL[w4 * 32 + l32] = l_pair;
    }
    __syncthreads();
    if (grp == 0) {
#pragma unroll
        for (int ic = 0; ic < 4; ++ic) {
            const fx4 c0 = lO[(ic * 4 + w4) * 64 + lane];
            const fx4 c1 = lO[((ic + 4) * 4 + w4) * 64 + lane];
#pragma unroll
            for (int r = 0; r < 4; ++r) { ov0[ic * 4 + r] += c0[r]; ov1[ic * 4 + r] += c1[r]; }
        }
        const float inv_l = 1.0f / (l_pair + lL[w4 * 32 + l32]);
#pragma unroll
        for (int dt = 0; dt < 2; ++dt)
#pragma unroll
            for (int rg2 = 0; rg2 < 4; ++rg2) {
                bf16x4 o4;
#pragma unroll
                for (int r = 0; r < 4; ++r)
                    o4[r] = (__bf16)((dt ? ov1[rg2 * 4 + r] : ov0[rg2 * 4 + r]) * inv_l);
                const int col = h * 64 + dt * 32 + rg2 * 8 + hi * 4;
                *(bf16x4*)(O + (size_t)qrow * 2048 + col) = o4;
            }
    }
}

// ----------------------------------------------------------------------------
extern "C" void kernel_launch(void* const* d_in, const int* in_sizes, int n_in,
                              void* d_out, int out_size, void* d_ws, size_t ws_size,
                              hipStream_t stream) {
    const float* x  = (const float*)d_in[0];
    const float* wq = (const float*)d_in[1];
    const float* wk = (const float*)d_in[2];
    const float* wv = (const float*)d_in[3];
    const float* wo = (const float*)d_in[4];
    float* out = (float*)d_out;
    char* ws = (char*)d_ws;

    __bf16* Xb    = (__bf16*)ws;                        // [0, 8M)
    __bf16* WqkvT = (__bf16*)(ws + ((size_t)8 << 20));  // [8M, 20M)  3072 x 2048
    __bf16* WoT   = (__bf16*)(ws + ((size_t)20 << 20)); // [20M, 28M) 2048 x 2048
    __bf16* Qr    = (__bf16*)(ws + ((size_t)28 << 20)); // [28M, 36M) 32 x 2048 x 64
    __bf16* Kr    = (__bf16*)(ws + ((size_t)36 << 20)); // [36M, 38M)  8 x 2048 x 64
    __bf16* Vt    = (__bf16*)(ws + ((size_t)38 << 20)); // [38M, 40M)  8 x 64 x 2048
    __bf16* Ob    = (__bf16*)(ws + ((size_t)40 << 20)); // [40M, 48M) 2048 x 2048
    float*  Cp    = (float*)ws;                         // [0, 16.8M) split-K partial (Xb/WqkvT dead)

    cast_x<<<4096, 256, 0, stream>>>((const float4*)x, Xb);
    transpose_all<<<dim3(160, 64), 256, 0, stream>>>(wq, wk, wv, wo, WqkvT, WoT);

    gemm_qkv<<<dim3(16, 48), 256, 0, stream>>>(Xb, WqkvT, Qr, Kr, Vt);
    flash_attn<<<dim3(16, 32), 512, 0, stream>>>(Qr, Kr, Vt, Ob);
    gemm_bt_sk<<<dim3(16, 16, 2), 256, 0, stream>>>(Ob, WoT, out, Cp, 2048, 2048, 2048);
    reduce_add<<<4096, 256, 0, stream>>>((float4*)out, (const float4*)Cp);
}

// Round 7
// 227.987 us; speedup vs baseline: 1.0179x; 1.0179x over previous
//
#include <hip/hip_runtime.h>
#include <hip/hip_bf16.h>

typedef __bf16 bf16x8 __attribute__((ext_vector_type(8)));
typedef __bf16 bf16x4 __attribute__((ext_vector_type(4)));
typedef float fx4 __attribute__((ext_vector_type(4)));
typedef float fx16 __attribute__((ext_vector_type(16)));

#define AS1 __attribute__((address_space(1)))
#define AS3 __attribute__((address_space(3)))

// ---------------------------------------------------------------- cast x -> bf16
__global__ __launch_bounds__(256) void cast_x(const float4* __restrict__ X, __bf16* __restrict__ Xb) {
    int i = blockIdx.x * 256 + threadIdx.x;
    float4 v = X[i];
    bf16x4 o = { (__bf16)v.x, (__bf16)v.y, (__bf16)v.z, (__bf16)v.w };
    *(bf16x4*)(Xb + (size_t)i * 4) = o;
}

// ------------------------------------------------- all 4 weight transposes in one launch
__global__ __launch_bounds__(256) void transpose_all(const float* __restrict__ wq, const float* __restrict__ wk,
                                                     const float* __restrict__ wv, const float* __restrict__ wo,
                                                     __bf16* __restrict__ WqkvT, __bf16* __restrict__ WoT) {
    constexpr int K = 2048;
    __shared__ float t[32][33];
    const int bx = blockIdx.x;
    const float* W; __bf16* Wt; int N, n0;
    if (bx < 64)      { W = wq; Wt = WqkvT;                        N = 2048; n0 = bx * 32; }
    else if (bx < 80) { W = wk; Wt = WqkvT + (size_t)2048 * 2048;  N = 512;  n0 = (bx - 64) * 32; }
    else if (bx < 96) { W = wv; Wt = WqkvT + (size_t)2560 * 2048;  N = 512;  n0 = (bx - 80) * 32; }
    else              { W = wo; Wt = WoT;                          N = 2048; n0 = (bx - 96) * 32; }
    const int tx = threadIdx.x & 31, ty = threadIdx.x >> 5;
    const int k0 = blockIdx.y * 32;
#pragma unroll
    for (int i = 0; i < 4; ++i)
        t[ty + i * 8][tx] = W[(size_t)(k0 + ty + i * 8) * N + n0 + tx];
    __syncthreads();
#pragma unroll
    for (int i = 0; i < 4; ++i)
        Wt[(size_t)(n0 + ty + i * 8) * K + k0 + tx] = (__bf16)t[tx][ty + i * 8];
}

// ------------------------------------------------- QKV GEMM, BN=64, BK=64 (2 sub-steps / barrier pair)
// A: 2048x2048 bf16, Bt: 3072x2048 bf16. grid (16, 48) = 768 blocks (3/CU).
// LDS as split k-halves so global_load_lds dst stays base+lane*16 (no pad).
__global__ __launch_bounds__(256) void gemm_qkv(const __bf16* __restrict__ A, const __bf16* __restrict__ Bt,
                                                __bf16* __restrict__ Qr, __bf16* __restrict__ Kr,
                                                __bf16* __restrict__ Vt) {
    constexpr int K = 2048;
    __shared__ __align__(16) __bf16 lA[2][128 * 32];
    __shared__ __align__(16) __bf16 lB[2][64 * 32];
    const int tid = threadIdx.x;
    const int wave = tid >> 6, lane = tid & 63;
    const int quad = lane >> 4, l16 = lane & 15;
    const int m0 = blockIdx.x * 128, n0 = blockIdx.y * 64;
    fx4 acc[2][4] = {};

    // 24 chunks of 1KB: A idx 0..15 (kh = idx&1, s = idx>>1), B idx 16..23.
    // chunk lane map: row = s*16 + (lane>>2), col = kh*32 + (lane&3)*8; dst = lX[kh] + s*512 + lane*8
    const __bf16* csrc[6]; __bf16* cdst[6];
#pragma unroll
    for (int it = 0; it < 6; ++it) {
        const int idx = wave * 6 + it;
        const int r4 = lane >> 2, c8 = (lane & 3) * 8;
        if (idx < 16) {
            const int kh = idx & 1, s = idx >> 1;
            csrc[it] = A + (size_t)(m0 + s * 16 + r4) * K + kh * 32 + c8;
            cdst[it] = &lA[kh][s * 512 + lane * 8];
        } else {
            const int b = idx - 16, kh = b & 1, s = b >> 1;
            csrc[it] = Bt + (size_t)(n0 + s * 16 + r4) * K + kh * 32 + c8;
            cdst[it] = &lB[kh][s * 512 + lane * 8];
        }
    }

    for (int k0 = 0; k0 < K; k0 += 64) {
        __syncthreads();
#pragma unroll
        for (int it = 0; it < 6; ++it)
            __builtin_amdgcn_global_load_lds((const AS1 void*)(csrc[it] + k0),
                                             (AS3 void*)cdst[it], 16, 0, 0);
        __builtin_amdgcn_s_waitcnt(0);
        __syncthreads();

#pragma unroll
        for (int kc = 0; kc < 2; ++kc) {
            bf16x8 af[2], bfr[4];
#pragma unroll
            for (int i = 0; i < 2; ++i) af[i] = *(const bf16x8*)&lA[kc][(wave * 32 + i * 16 + l16) * 32 + quad * 8];
#pragma unroll
            for (int j = 0; j < 4; ++j) bfr[j] = *(const bf16x8*)&lB[kc][(j * 16 + l16) * 32 + quad * 8];
#pragma unroll
            for (int i = 0; i < 2; ++i)
#pragma unroll
                for (int j = 0; j < 4; ++j)
                    acc[i][j] = __builtin_amdgcn_mfma_f32_16x16x32_bf16(af[i], bfr[j], acc[i][j], 0, 0, 0);
        }
    }

    // fused epilogue: d = j*16 + l16, s = m0 + wave*32 + i*16 + quad*4 + r
    const int by = blockIdx.y;
    if (by < 40) {
        const float scale = (by < 32) ? 0.18033688011112042f : 1.0f;   // Q: 0.125*log2(e)
        __bf16* base = (by < 32) ? (Qr + (size_t)by * 2048 * 64)
                                 : (Kr + (size_t)(by - 32) * 2048 * 64);
#pragma unroll
        for (int jj = 0; jj < 2; ++jj) {
            const int dlo = jj * 16 + l16;
            const float inv = __builtin_amdgcn_exp2f(-(float)dlo * 0.41524101186092029f);
#pragma unroll
            for (int i = 0; i < 2; ++i)
#pragma unroll
                for (int r = 0; r < 4; ++r) {
                    const int s = m0 + wave * 32 + i * 16 + quad * 4 + r;
                    float sn, cs;
                    __sincosf((float)s * inv, &sn, &cs);
                    const float lo = acc[i][jj][r], hv = acc[i][jj + 2][r];
                    base[(size_t)s * 64 + dlo]      = (__bf16)((lo * cs - hv * sn) * scale);
                    base[(size_t)s * 64 + dlo + 32] = (__bf16)((hv * cs + lo * sn) * scale);
                }
        }
    } else {
        __bf16* vb = Vt + (size_t)(by - 40) * 64 * 2048;
#pragma unroll
        for (int i = 0; i < 2; ++i)
#pragma unroll
            for (int j = 0; j < 4; ++j) {
                const int d = j * 16 + l16;
                const int s0 = m0 + wave * 32 + i * 16 + quad * 4;
                bf16x4 p;
#pragma unroll
                for (int r = 0; r < 4; ++r) p[r] = (__bf16)acc[i][j][r];
                *(bf16x4*)&vb[(size_t)d * 2048 + s0] = p;
            }
    }
}

// ------------------------------------------------- out-projection GEMM, split-K=2 (unchanged)
__global__ __launch_bounds__(256) void gemm_bt_sk(const __bf16* __restrict__ A, const __bf16* __restrict__ Bt,
                                                  float* __restrict__ C0, float* __restrict__ C1,
                                                  int M, int N, int K) {
    __shared__ __align__(16) __bf16 lA[128 * 32];
    __shared__ __align__(16) __bf16 lB[128 * 32];
    const int tid = threadIdx.x;
    const int wave = tid >> 6, lane = tid & 63;
    const int quad = lane >> 4, l16 = lane & 15;
    const int m0 = blockIdx.x * 128, n0 = blockIdx.y * 128;
    const int kz = blockIdx.z;
    const int kbeg = kz * (K >> 1), kend = kbeg + (K >> 1);
    float* C = kz ? C1 : C0;
    const int wm = (wave >> 1) * 64, wn = (wave & 1) * 64;
    fx4 acc[4][4] = {};

    const int st0 = wave * 1024;
    const int st1 = 4096 + wave * 1024;
    const int r0 = (st0 + lane * 16) >> 6, c0 = ((st0 + lane * 16) & 63) >> 1;
    const int r1 = (st1 + lane * 16) >> 6, c1 = ((st1 + lane * 16) & 63) >> 1;

    for (int k0 = kbeg; k0 < kend; k0 += 32) {
        __syncthreads();
        __builtin_amdgcn_global_load_lds((const AS1 void*)(A + (size_t)(m0 + r0) * K + k0 + c0),
                                         (AS3 void*)(lA + (st0 >> 1)), 16, 0, 0);
        __builtin_amdgcn_global_load_lds((const AS1 void*)(A + (size_t)(m0 + r1) * K + k0 + c1),
                                         (AS3 void*)(lA + (st1 >> 1)), 16, 0, 0);
        __builtin_amdgcn_global_load_lds((const AS1 void*)(Bt + (size_t)(n0 + r0) * K + k0 + c0),
                                         (AS3 void*)(lB + (st0 >> 1)), 16, 0, 0);
        __builtin_amdgcn_global_load_lds((const AS1 void*)(Bt + (size_t)(n0 + r1) * K + k0 + c1),
                                         (AS3 void*)(lB + (st1 >> 1)), 16, 0, 0);
        __builtin_amdgcn_s_waitcnt(0);
        __syncthreads();

        bf16x8 af[4], bfr[4];
#pragma unroll
        for (int i = 0; i < 4; ++i) af[i] = *(const bf16x8*)&lA[(wm + i * 16 + l16) * 32 + quad * 8];
#pragma unroll
        for (int j = 0; j < 4; ++j) bfr[j] = *(const bf16x8*)&lB[(wn + j * 16 + l16) * 32 + quad * 8];
#pragma unroll
        for (int i = 0; i < 4; ++i)
#pragma unroll
            for (int j = 0; j < 4; ++j)
                acc[i][j] = __builtin_amdgcn_mfma_f32_16x16x32_bf16(af[i], bfr[j], acc[i][j], 0, 0, 0);
    }
#pragma unroll
    for (int i = 0; i < 4; ++i)
#pragma unroll
        for (int j = 0; j < 4; ++j) {
            const int row = m0 + wm + i * 16 + quad * 4;
            const int col = n0 + wn + j * 16 + l16;
#pragma unroll
            for (int r = 0; r < 4; ++r)
                C[(size_t)(row + r) * N + col] = acc[i][j][r];
        }
}

// ------------------------------------------------- out += partial (deterministic split-K reduce)
__global__ __launch_bounds__(256) void reduce_add(float4* __restrict__ out, const float4* __restrict__ p) {
    const int i = blockIdx.x * 256 + threadIdx.x;
    float4 a = out[i];
    const float4 b = p[i];
    a.x += b.x; a.y += b.y; a.z += b.z; a.w += b.w;
    out[i] = a;
}

// ------------------------------------------------- flash attention: no-P-LDS via permuted V
// grid (16 q-tiles of 128, 32 heads), 256 thr = 4 waves; wave owns 32 q, all 32 key-tiles.
// S^T = K.Q^T (C-layout: q = lane&31, key = (rg&3)+8*(rg>>2)+4*hi). PV B-operand is built
// DIRECTLY from score regs: for chunk c of half h, B-frag = pack(sc_h[c*8..c*8+8)) -- valid
// because V is staged into LDS with key-index bits 2<->3 swapped (slot = sigma(key)), making
// the per-lane k-permutation consistent between A (V) and B (P). MFMA is permutation-
// invariant over k, so no P LDS round-trip and no shuffles are needed.
__global__ __launch_bounds__(256, 4) void flash_attn(const __bf16* __restrict__ Qr, const __bf16* __restrict__ Kr,
                                                     const __bf16* __restrict__ Vt, __bf16* __restrict__ O) {
    constexpr int S = 2048;
    __shared__ __align__(16) __bf16 lK[64 * 72];   // [key][d] stride 72
    __shared__ __align__(16) __bf16 lV[64 * 72];   // [d][slot] stride 72, slot = key w/ bits2<->3 swapped
    const int qt = blockIdx.x, h = blockIdx.y, kvh = h >> 2;
    const int tid = threadIdx.x, wave = tid >> 6, lane = tid & 63;
    const int l32 = lane & 31, hi = lane >> 5;

    const int qrow = qt * 128 + wave * 32 + l32;
    const __bf16* qptr = Qr + ((size_t)h * S + qrow) * 64;
    bf16x8 qf[4];
#pragma unroll
    for (int kc = 0; kc < 4; ++kc) qf[kc] = *(const bf16x8*)(qptr + kc * 16 + hi * 8);

    const __bf16* Kbase = Kr + (size_t)kvh * S * 64;
    const __bf16* Vbase = Vt + (size_t)kvh * 64 * S;

    const int krow = tid >> 3;                 // 0..31
    const int kcol = (tid & 7) * 8;
    const int vslot = (kcol & 48) | ((kcol & 8) >> 1);   // permuted dest of keys [kcol, kcol+4)

    bf16x8 kreg0 = *(const bf16x8*)(Kbase + (size_t)krow * 64 + kcol);
    bf16x8 kreg1 = *(const bf16x8*)(Kbase + (size_t)(32 + krow) * 64 + kcol);
    bf16x8 vreg0 = *(const bf16x8*)(Vbase + (size_t)krow * S + kcol);
    bf16x8 vreg1 = *(const bf16x8*)(Vbase + (size_t)(32 + krow) * S + kcol);

    fx16 ov0, ov1;
#pragma unroll
    for (int i = 0; i < 16; ++i) { ov0[i] = 0.f; ov1[i] = 0.f; }
    float l_acc = 0.f;

    for (int kt = 0; kt < 32; ++kt) {
        __syncthreads();
        *(bf16x8*)&lK[krow * 72 + kcol] = kreg0;
        *(bf16x8*)&lK[(32 + krow) * 72 + kcol] = kreg1;
        bf16x4 v0lo = { vreg0[0], vreg0[1], vreg0[2], vreg0[3] };
        bf16x4 v0hi = { vreg0[4], vreg0[5], vreg0[6], vreg0[7] };
        bf16x4 v1lo = { vreg1[0], vreg1[1], vreg1[2], vreg1[3] };
        bf16x4 v1hi = { vreg1[4], vreg1[5], vreg1[6], vreg1[7] };
        *(bf16x4*)&lV[krow * 72 + vslot]            = v0lo;
        *(bf16x4*)&lV[krow * 72 + vslot + 8]        = v0hi;
        *(bf16x4*)&lV[(32 + krow) * 72 + vslot]     = v1lo;
        *(bf16x4*)&lV[(32 + krow) * 72 + vslot + 8] = v1hi;
        const int ktn = (kt + 1 < 32) ? kt + 1 : kt;
        kreg0 = *(const bf16x8*)(Kbase + (size_t)(ktn * 64 + krow) * 64 + kcol);
        kreg1 = *(const bf16x8*)(Kbase + (size_t)(ktn * 64 + 32 + krow) * 64 + kcol);
        vreg0 = *(const bf16x8*)(Vbase + (size_t)krow * S + ktn * 64 + kcol);
        vreg1 = *(const bf16x8*)(Vbase + (size_t)(32 + krow) * S + ktn * 64 + kcol);
        __syncthreads();

        // S^T = K . Q^T  (k-chunks of 16 d)
        fx16 sc0, sc1;
#pragma unroll
        for (int i = 0; i < 16; ++i) { sc0[i] = 0.f; sc1[i] = 0.f; }
#pragma unroll
        for (int kc = 0; kc < 4; ++kc) {
            const bf16x8 a0 = *(const bf16x8*)&lK[l32 * 72 + kc * 16 + hi * 8];
            const bf16x8 a1 = *(const bf16x8*)&lK[(32 + l32) * 72 + kc * 16 + hi * 8];
            sc0 = __builtin_amdgcn_mfma_f32_32x32x16_bf16(a0, qf[kc], sc0, 0, 0, 0);
            sc1 = __builtin_amdgcn_mfma_f32_32x32x16_bf16(a1, qf[kc], sc1, 0, 0, 0);
        }

        // fixed-max softmax (p = exp2(s), Q pre-scaled) fused straight into PV
#pragma unroll
        for (int h2 = 0; h2 < 2; ++h2) {
#pragma unroll
            for (int c = 0; c < 2; ++c) {
                bf16x8 pb;
#pragma unroll
                for (int j = 0; j < 8; ++j) {
                    const float sv = h2 ? sc1[c * 8 + j] : sc0[c * 8 + j];
                    const float p = __builtin_amdgcn_exp2f(sv);
                    l_acc += p;
                    pb[j] = (__bf16)p;
                }
                const int kcv = h2 * 2 + c;
                const bf16x8 va0 = *(const bf16x8*)&lV[l32 * 72 + kcv * 16 + hi * 8];
                const bf16x8 va1 = *(const bf16x8*)&lV[(32 + l32) * 72 + kcv * 16 + hi * 8];
                ov0 = __builtin_amdgcn_mfma_f32_32x32x16_bf16(va0, pb, ov0, 0, 0, 0);
                ov1 = __builtin_amdgcn_mfma_f32_32x32x16_bf16(va1, pb, ov1, 0, 0, 0);
            }
        }
    }

    // l: lane covers keys with pattern over hi; partner lane^32 holds the complement
    const float l_tot = l_acc + __shfl_xor(l_acc, 32, 64);
    const float inv_l = 1.0f / l_tot;

    // epilogue: O[qrow][h*64 + d], d = dt*32 + rg2*8 + hi*4 + r
#pragma unroll
    for (int dt = 0; dt < 2; ++dt)
#pragma unroll
        for (int rg2 = 0; rg2 < 4; ++rg2) {
            bf16x4 o4;
#pragma unroll
            for (int r = 0; r < 4; ++r)
                o4[r] = (__bf16)((dt ? ov1[rg2 * 4 + r] : ov0[rg2 * 4 + r]) * inv_l);
            const int col = h * 64 + dt * 32 + rg2 * 8 + hi * 4;
            *(bf16x4*)(O + (size_t)qrow * 2048 + col) = o4;
        }
}

// ----------------------------------------------------------------------------
extern "C" void kernel_launch(void* const* d_in, const int* in_sizes, int n_in,
                              void* d_out, int out_size, void* d_ws, size_t ws_size,
                              hipStream_t stream) {
    const float* x  = (const float*)d_in[0];
    const float* wq = (const float*)d_in[1];
    const float* wk = (const float*)d_in[2];
    const float* wv = (const float*)d_in[3];
    const float* wo = (const float*)d_in[4];
    float* out = (float*)d_out;
    char* ws = (char*)d_ws;

    __bf16* Xb    = (__bf16*)ws;                        // [0, 8M)
    __bf16* WqkvT = (__bf16*)(ws + ((size_t)8 << 20));  // [8M, 20M)  3072 x 2048
    __bf16* WoT   = (__bf16*)(ws + ((size_t)20 << 20)); // [20M, 28M) 2048 x 2048
    __bf16* Qr    = (__bf16*)(ws + ((size_t)28 << 20)); // [28M, 36M) 32 x 2048 x 64
    __bf16* Kr    = (__bf16*)(ws + ((size_t)36 << 20)); // [36M, 38M)  8 x 2048 x 64
    __bf16* Vt    = (__bf16*)(ws + ((size_t)38 << 20)); // [38M, 40M)  8 x 64 x 2048
    __bf16* Ob    = (__bf16*)(ws + ((size_t)40 << 20)); // [40M, 48M) 2048 x 2048
    float*  Cp    = (float*)ws;                         // [0, 16.8M) split-K partial (Xb/WqkvT dead)

    cast_x<<<4096, 256, 0, stream>>>((const float4*)x, Xb);
    transpose_all<<<dim3(160, 64), 256, 0, stream>>>(wq, wk, wv, wo, WqkvT, WoT);

    gemm_qkv<<<dim3(16, 48), 256, 0, stream>>>(Xb, WqkvT, Qr, Kr, Vt);
    flash_attn<<<dim3(16, 32), 256, 0, stream>>>(Qr, Kr, Vt, Ob);
    gemm_bt_sk<<<dim3(16, 16, 2), 256, 0, stream>>>(Ob, WoT, out, Cp, 2048, 2048, 2048);
    reduce_add<<<4096, 256, 0, stream>>>((float4*)out, (const float4*)Cp);
}

// Round 8
// 222.844 us; speedup vs baseline: 1.0414x; 1.0231x over previous
//
#include <hip/hip_runtime.h>
#include <hip/hip_bf16.h>

typedef __bf16 bf16x8 __attribute__((ext_vector_type(8)));
typedef __bf16 bf16x4 __attribute__((ext_vector_type(4)));
typedef float fx4 __attribute__((ext_vector_type(4)));
typedef float fx16 __attribute__((ext_vector_type(16)));

#define AS1 __attribute__((address_space(1)))
#define AS3 __attribute__((address_space(3)))

// ---------------------------------------------------------------- cast x -> bf16
__global__ __launch_bounds__(256) void cast_x(const float4* __restrict__ X, __bf16* __restrict__ Xb) {
    int i = blockIdx.x * 256 + threadIdx.x;
    float4 v = X[i];
    bf16x4 o = { (__bf16)v.x, (__bf16)v.y, (__bf16)v.z, (__bf16)v.w };
    *(bf16x4*)(Xb + (size_t)i * 4) = o;
}

// ------------------------------------------------- all 4 weight transposes in one launch
__global__ __launch_bounds__(256) void transpose_all(const float* __restrict__ wq, const float* __restrict__ wk,
                                                     const float* __restrict__ wv, const float* __restrict__ wo,
                                                     __bf16* __restrict__ WqkvT, __bf16* __restrict__ WoT) {
    constexpr int K = 2048;
    __shared__ float t[32][33];
    const int bx = blockIdx.x;
    const float* W; __bf16* Wt; int N, n0;
    if (bx < 64)      { W = wq; Wt = WqkvT;                        N = 2048; n0 = bx * 32; }
    else if (bx < 80) { W = wk; Wt = WqkvT + (size_t)2048 * 2048;  N = 512;  n0 = (bx - 64) * 32; }
    else if (bx < 96) { W = wv; Wt = WqkvT + (size_t)2560 * 2048;  N = 512;  n0 = (bx - 80) * 32; }
    else              { W = wo; Wt = WoT;                          N = 2048; n0 = (bx - 96) * 32; }
    const int tx = threadIdx.x & 31, ty = threadIdx.x >> 5;
    const int k0 = blockIdx.y * 32;
#pragma unroll
    for (int i = 0; i < 4; ++i)
        t[ty + i * 8][tx] = W[(size_t)(k0 + ty + i * 8) * N + n0 + tx];
    __syncthreads();
#pragma unroll
    for (int i = 0; i < 4; ++i)
        Wt[(size_t)(n0 + ty + i * 8) * K + k0 + tx] = (__bf16)t[tx][ty + i * 8];
}

// ------------------------------------------------- QKV GEMM, BN=64, BK=64, fused RoPE/split
__global__ __launch_bounds__(256) void gemm_qkv(const __bf16* __restrict__ A, const __bf16* __restrict__ Bt,
                                                __bf16* __restrict__ Qr, __bf16* __restrict__ Kr,
                                                __bf16* __restrict__ Vt) {
    constexpr int K = 2048;
    __shared__ __align__(16) __bf16 lA[2][128 * 32];
    __shared__ __align__(16) __bf16 lB[2][64 * 32];
    const int tid = threadIdx.x;
    const int wave = tid >> 6, lane = tid & 63;
    const int quad = lane >> 4, l16 = lane & 15;
    const int m0 = blockIdx.x * 128, n0 = blockIdx.y * 64;
    fx4 acc[2][4] = {};

    const __bf16* csrc[6]; __bf16* cdst[6];
#pragma unroll
    for (int it = 0; it < 6; ++it) {
        const int idx = wave * 6 + it;
        const int r4 = lane >> 2, c8 = (lane & 3) * 8;
        if (idx < 16) {
            const int kh = idx & 1, s = idx >> 1;
            csrc[it] = A + (size_t)(m0 + s * 16 + r4) * K + kh * 32 + c8;
            cdst[it] = &lA[kh][s * 512 + lane * 8];
        } else {
            const int b = idx - 16, kh = b & 1, s = b >> 1;
            csrc[it] = Bt + (size_t)(n0 + s * 16 + r4) * K + kh * 32 + c8;
            cdst[it] = &lB[kh][s * 512 + lane * 8];
        }
    }

    for (int k0 = 0; k0 < K; k0 += 64) {
        __syncthreads();
#pragma unroll
        for (int it = 0; it < 6; ++it)
            __builtin_amdgcn_global_load_lds((const AS1 void*)(csrc[it] + k0),
                                             (AS3 void*)cdst[it], 16, 0, 0);
        __builtin_amdgcn_s_waitcnt(0);
        __syncthreads();

#pragma unroll
        for (int kc = 0; kc < 2; ++kc) {
            bf16x8 af[2], bfr[4];
#pragma unroll
            for (int i = 0; i < 2; ++i) af[i] = *(const bf16x8*)&lA[kc][(wave * 32 + i * 16 + l16) * 32 + quad * 8];
#pragma unroll
            for (int j = 0; j < 4; ++j) bfr[j] = *(const bf16x8*)&lB[kc][(j * 16 + l16) * 32 + quad * 8];
#pragma unroll
            for (int i = 0; i < 2; ++i)
#pragma unroll
                for (int j = 0; j < 4; ++j)
                    acc[i][j] = __builtin_amdgcn_mfma_f32_16x16x32_bf16(af[i], bfr[j], acc[i][j], 0, 0, 0);
        }
    }

    const int by = blockIdx.y;
    if (by < 40) {
        const float scale = (by < 32) ? 0.18033688011112042f : 1.0f;   // Q: 0.125*log2(e)
        __bf16* base = (by < 32) ? (Qr + (size_t)by * 2048 * 64)
                                 : (Kr + (size_t)(by - 32) * 2048 * 64);
#pragma unroll
        for (int jj = 0; jj < 2; ++jj) {
            const int dlo = jj * 16 + l16;
            const float inv = __builtin_amdgcn_exp2f(-(float)dlo * 0.41524101186092029f);
#pragma unroll
            for (int i = 0; i < 2; ++i)
#pragma unroll
                for (int r = 0; r < 4; ++r) {
                    const int s = m0 + wave * 32 + i * 16 + quad * 4 + r;
                    float sn, cs;
                    __sincosf((float)s * inv, &sn, &cs);
                    const float lo = acc[i][jj][r], hv = acc[i][jj + 2][r];
                    base[(size_t)s * 64 + dlo]      = (__bf16)((lo * cs - hv * sn) * scale);
                    base[(size_t)s * 64 + dlo + 32] = (__bf16)((hv * cs + lo * sn) * scale);
                }
        }
    } else {
        __bf16* vb = Vt + (size_t)(by - 40) * 64 * 2048;
#pragma unroll
        for (int i = 0; i < 2; ++i)
#pragma unroll
            for (int j = 0; j < 4; ++j) {
                const int d = j * 16 + l16;
                const int s0 = m0 + wave * 32 + i * 16 + quad * 4;
                bf16x4 p;
#pragma unroll
                for (int r = 0; r < 4; ++r) p[r] = (__bf16)acc[i][j][r];
                *(bf16x4*)&vb[(size_t)d * 2048 + s0] = p;
            }
    }
}

// ------------------------------------------------- out-projection GEMM, split-K=2
__global__ __launch_bounds__(256) void gemm_bt_sk(const __bf16* __restrict__ A, const __bf16* __restrict__ Bt,
                                                  float* __restrict__ C0, float* __restrict__ C1,
                                                  int M, int N, int K) {
    __shared__ __align__(16) __bf16 lA[128 * 32];
    __shared__ __align__(16) __bf16 lB[128 * 32];
    const int tid = threadIdx.x;
    const int wave = tid >> 6, lane = tid & 63;
    const int quad = lane >> 4, l16 = lane & 15;
    const int m0 = blockIdx.x * 128, n0 = blockIdx.y * 128;
    const int kz = blockIdx.z;
    const int kbeg = kz * (K >> 1), kend = kbeg + (K >> 1);
    float* C = kz ? C1 : C0;
    const int wm = (wave >> 1) * 64, wn = (wave & 1) * 64;
    fx4 acc[4][4] = {};

    const int st0 = wave * 1024;
    const int st1 = 4096 + wave * 1024;
    const int r0 = (st0 + lane * 16) >> 6, c0 = ((st0 + lane * 16) & 63) >> 1;
    const int r1 = (st1 + lane * 16) >> 6, c1 = ((st1 + lane * 16) & 63) >> 1;

    for (int k0 = kbeg; k0 < kend; k0 += 32) {
        __syncthreads();
        __builtin_amdgcn_global_load_lds((const AS1 void*)(A + (size_t)(m0 + r0) * K + k0 + c0),
                                         (AS3 void*)(lA + (st0 >> 1)), 16, 0, 0);
        __builtin_amdgcn_global_load_lds((const AS1 void*)(A + (size_t)(m0 + r1) * K + k0 + c1),
                                         (AS3 void*)(lA + (st1 >> 1)), 16, 0, 0);
        __builtin_amdgcn_global_load_lds((const AS1 void*)(Bt + (size_t)(n0 + r0) * K + k0 + c0),
                                         (AS3 void*)(lB + (st0 >> 1)), 16, 0, 0);
        __builtin_amdgcn_global_load_lds((const AS1 void*)(Bt + (size_t)(n0 + r1) * K + k0 + c1),
                                         (AS3 void*)(lB + (st1 >> 1)), 16, 0, 0);
        __builtin_amdgcn_s_waitcnt(0);
        __syncthreads();

        bf16x8 af[4], bfr[4];
#pragma unroll
        for (int i = 0; i < 4; ++i) af[i] = *(const bf16x8*)&lA[(wm + i * 16 + l16) * 32 + quad * 8];
#pragma unroll
        for (int j = 0; j < 4; ++j) bfr[j] = *(const bf16x8*)&lB[(wn + j * 16 + l16) * 32 + quad * 8];
#pragma unroll
        for (int i = 0; i < 4; ++i)
#pragma unroll
            for (int j = 0; j < 4; ++j)
                acc[i][j] = __builtin_amdgcn_mfma_f32_16x16x32_bf16(af[i], bfr[j], acc[i][j], 0, 0, 0);
    }
#pragma unroll
    for (int i = 0; i < 4; ++i)
#pragma unroll
        for (int j = 0; j < 4; ++j) {
            const int row = m0 + wm + i * 16 + quad * 4;
            const int col = n0 + wn + j * 16 + l16;
#pragma unroll
            for (int r = 0; r < 4; ++r)
                C[(size_t)(row + r) * N + col] = acc[i][j][r];
        }
}

// ------------------------------------------------- out += partial (deterministic split-K reduce)
__global__ __launch_bounds__(256) void reduce_add(float4* __restrict__ out, const float4* __restrict__ p) {
    const int i = blockIdx.x * 256 + threadIdx.x;
    float4 a = out[i];
    const float4 b = p[i];
    a.x += b.x; a.y += b.y; a.z += b.z; a.w += b.w;
    out[i] = a;
}

// ------------------------------------------------- flash attention: no-P-LDS + 8-wave in-block split-K
// grid (16 q-tiles of 128, 32 heads), 512 thr = 8 waves. Waves 0-3 (grp 0) even key-tiles,
// waves 4-7 (grp 1) odd key-tiles, private lK/lV per group (16 iters each).
// Inner loop = R6's permuted-V no-P scheme: PV B-operand packed straight from exp2'd score
// regs; V staged with key bits2<->3 swapped so the per-lane k-permutation matches.
// Fixed-max softmax -> cross-group combine is plain adds through LDS after the loop.
// ALL shared memory is ONE declared array (combine buffers overlay it after the loop) --
// no cross-array aliasing (R5 bug class excluded by construction).
__global__ __launch_bounds__(512, 4) void flash_attn(const __bf16* __restrict__ Qr, const __bf16* __restrict__ Kr,
                                                     const __bf16* __restrict__ Vt, __bf16* __restrict__ O) {
    constexpr int S = 2048;
    __shared__ __align__(16) __bf16 smem[4 * 64 * 72];   // 36864 B: [grp0 K][grp0 V][grp1 K][grp1 V]
    const int qt = blockIdx.x, h = blockIdx.y, kvh = h >> 2;
    const int tid = threadIdx.x, wave = tid >> 6, lane = tid & 63;
    const int grp = wave >> 2, w4 = wave & 3;
    const int l32 = lane & 31, hi = lane >> 5;

    __bf16* lKg = smem + grp * 2 * 4608;
    __bf16* lVg = lKg + 4608;

    const int qrow = qt * 128 + w4 * 32 + l32;
    const __bf16* qptr = Qr + ((size_t)h * S + qrow) * 64;
    bf16x8 qf[4];
#pragma unroll
    for (int kc = 0; kc < 4; ++kc) qf[kc] = *(const bf16x8*)(qptr + kc * 16 + hi * 8);

    const __bf16* Kbase = Kr + (size_t)kvh * S * 64;
    const __bf16* Vbase = Vt + (size_t)kvh * 64 * S;

    const int gtid = tid & 255;
    const int krow = gtid >> 3;                 // 0..31
    const int kcol = (gtid & 7) * 8;
    const int vslot = (kcol & 48) | ((kcol & 8) >> 1);   // permuted dest of keys [kcol, kcol+4)

    // prefetch this group's first tile (kt = grp)
    bf16x8 kreg0 = *(const bf16x8*)(Kbase + (size_t)(grp * 64 + krow) * 64 + kcol);
    bf16x8 kreg1 = *(const bf16x8*)(Kbase + (size_t)(grp * 64 + 32 + krow) * 64 + kcol);
    bf16x8 vreg0 = *(const bf16x8*)(Vbase + (size_t)krow * S + grp * 64 + kcol);
    bf16x8 vreg1 = *(const bf16x8*)(Vbase + (size_t)(32 + krow) * S + grp * 64 + kcol);

    fx16 ov0, ov1;
#pragma unroll
    for (int i = 0; i < 16; ++i) { ov0[i] = 0.f; ov1[i] = 0.f; }
    float l_acc = 0.f;

    for (int it = 0; it < 16; ++it) {
        const int kt = it * 2 + grp;
        __syncthreads();
        *(bf16x8*)&lKg[krow * 72 + kcol] = kreg0;
        *(bf16x8*)&lKg[(32 + krow) * 72 + kcol] = kreg1;
        bf16x4 v0lo = { vreg0[0], vreg0[1], vreg0[2], vreg0[3] };
        bf16x4 v0hi = { vreg0[4], vreg0[5], vreg0[6], vreg0[7] };
        bf16x4 v1lo = { vreg1[0], vreg1[1], vreg1[2], vreg1[3] };
        bf16x4 v1hi = { vreg1[4], vreg1[5], vreg1[6], vreg1[7] };
        *(bf16x4*)&lVg[krow * 72 + vslot]            = v0lo;
        *(bf16x4*)&lVg[krow * 72 + vslot + 8]        = v0hi;
        *(bf16x4*)&lVg[(32 + krow) * 72 + vslot]     = v1lo;
        *(bf16x4*)&lVg[(32 + krow) * 72 + vslot + 8] = v1hi;
        const int ktn = (it + 1 < 16) ? kt + 2 : kt;
        kreg0 = *(const bf16x8*)(Kbase + (size_t)(ktn * 64 + krow) * 64 + kcol);
        kreg1 = *(const bf16x8*)(Kbase + (size_t)(ktn * 64 + 32 + krow) * 64 + kcol);
        vreg0 = *(const bf16x8*)(Vbase + (size_t)krow * S + ktn * 64 + kcol);
        vreg1 = *(const bf16x8*)(Vbase + (size_t)(32 + krow) * S + ktn * 64 + kcol);
        __syncthreads();

        // S^T = K . Q^T  (k-chunks of 16 d)
        fx16 sc0, sc1;
#pragma unroll
        for (int i = 0; i < 16; ++i) { sc0[i] = 0.f; sc1[i] = 0.f; }
#pragma unroll
        for (int kc = 0; kc < 4; ++kc) {
            const bf16x8 a0 = *(const bf16x8*)&lKg[l32 * 72 + kc * 16 + hi * 8];
            const bf16x8 a1 = *(const bf16x8*)&lKg[(32 + l32) * 72 + kc * 16 + hi * 8];
            sc0 = __builtin_amdgcn_mfma_f32_32x32x16_bf16(a0, qf[kc], sc0, 0, 0, 0);
            sc1 = __builtin_amdgcn_mfma_f32_32x32x16_bf16(a1, qf[kc], sc1, 0, 0, 0);
        }

        // fixed-max softmax (p = exp2(s), Q pre-scaled) fused straight into PV
#pragma unroll
        for (int h2 = 0; h2 < 2; ++h2) {
#pragma unroll
            for (int c = 0; c < 2; ++c) {
                bf16x8 pb;
#pragma unroll
                for (int j = 0; j < 8; ++j) {
                    const float sv = h2 ? sc1[c * 8 + j] : sc0[c * 8 + j];
                    const float p = __builtin_amdgcn_exp2f(sv);
                    l_acc += p;
                    pb[j] = (__bf16)p;
                }
                const int kcv = h2 * 2 + c;
                const bf16x8 va0 = *(const bf16x8*)&lVg[l32 * 72 + kcv * 16 + hi * 8];
                const bf16x8 va1 = *(const bf16x8*)&lVg[(32 + l32) * 72 + kcv * 16 + hi * 8];
                ov0 = __builtin_amdgcn_mfma_f32_32x32x16_bf16(va0, pb, ov0, 0, 0, 0);
                ov1 = __builtin_amdgcn_mfma_f32_32x32x16_bf16(va1, pb, ov1, 0, 0, 0);
            }
        }
    }

    // per-wave l over this group's keys (partner lane^32 holds complement)
    const float l_pair = l_acc + __shfl_xor(l_acc, 32, 64);

    // cross-group combine, overlaid on smem: lO 32768 B + lL 512 B <= 36864 B.
    fx4* lO = (fx4*)smem;                        // [8 chunks][4 w4][64 lanes]
    float* lL = (float*)(smem + 16384);          // element offset 16384 = byte 32768
    __syncthreads();                             // all loop reads of smem done
    if (grp == 1) {
#pragma unroll
        for (int ic = 0; ic < 4; ++ic) {
            fx4 c0, c1;
#pragma unroll
            for (int r = 0; r < 4; ++r) { c0[r] = ov0[ic * 4 + r]; c1[r] = ov1[ic * 4 + r]; }
            lO[(ic * 4 + w4) * 64 + lane] = c0;
            lO[((ic + 4) * 4 + w4) * 64 + lane] = c1;
        }
        if (hi == 0) lL[w4 * 32 + l32] = l_pair;
    }
    __syncthreads();
    if (grp == 0) {
#pragma unroll
        for (int ic = 0; ic < 4; ++ic) {
            const fx4 c0 = lO[(ic * 4 + w4) * 64 + lane];
            const fx4 c1 = lO[((ic + 4) * 4 + w4) * 64 + lane];
#pragma unroll
            for (int r = 0; r < 4; ++r) { ov0[ic * 4 + r] += c0[r]; ov1[ic * 4 + r] += c1[r]; }
        }
        const float inv_l = 1.0f / (l_pair + lL[w4 * 32 + l32]);
#pragma unroll
        for (int dt = 0; dt < 2; ++dt)
#pragma unroll
            for (int rg2 = 0; rg2 < 4; ++rg2) {
                bf16x4 o4;
#pragma unroll
                for (int r = 0; r < 4; ++r)
                    o4[r] = (__bf16)((dt ? ov1[rg2 * 4 + r] : ov0[rg2 * 4 + r]) * inv_l);
                const int col = h * 64 + dt * 32 + rg2 * 8 + hi * 4;
                *(bf16x4*)(O + (size_t)qrow * 2048 + col) = o4;
            }
    }
}

// ----------------------------------------------------------------------------
extern "C" void kernel_launch(void* const* d_in, const int* in_sizes, int n_in,
                              void* d_out, int out_size, void* d_ws, size_t ws_size,
                              hipStream_t stream) {
    const float* x  = (const float*)d_in[0];
    const float* wq = (const float*)d_in[1];
    const float* wk = (const float*)d_in[2];
    const float* wv = (const float*)d_in[3];
    const float* wo = (const float*)d_in[4];
    float* out = (float*)d_out;
    char* ws = (char*)d_ws;

    __bf16* Xb    = (__bf16*)ws;                        // [0, 8M)
    __bf16* WqkvT = (__bf16*)(ws + ((size_t)8 << 20));  // [8M, 20M)  3072 x 2048
    __bf16* WoT   = (__bf16*)(ws + ((size_t)20 << 20)); // [20M, 28M) 2048 x 2048
    __bf16* Qr    = (__bf16*)(ws + ((size_t)28 << 20)); // [28M, 36M) 32 x 2048 x 64
    __bf16* Kr    = (__bf16*)(ws + ((size_t)36 << 20)); // [36M, 38M)  8 x 2048 x 64
    __bf16* Vt    = (__bf16*)(ws + ((size_t)38 << 20)); // [38M, 40M)  8 x 64 x 2048
    __bf16* Ob    = (__bf16*)(ws + ((size_t)40 << 20)); // [40M, 48M) 2048 x 2048
    float*  Cp    = (float*)ws;                         // [0, 16.8M) split-K partial (Xb/WqkvT dead)

    cast_x<<<4096, 256, 0, stream>>>((const float4*)x, Xb);
    transpose_all<<<dim3(160, 64), 256, 0, stream>>>(wq, wk, wv, wo, WqkvT, WoT);

    gemm_qkv<<<dim3(16, 48), 256, 0, stream>>>(Xb, WqkvT, Qr, Kr, Vt);
    flash_attn<<<dim3(16, 32), 512, 0, stream>>>(Qr, Kr, Vt, Ob);
    gemm_bt_sk<<<dim3(16, 16, 2), 256, 0, stream>>>(Ob, WoT, out, Cp, 2048, 2048, 2048);
    reduce_add<<<4096, 256, 0, stream>>>((float4*)out, (const float4*)Cp);
}

// Round 9
// 221.073 us; speedup vs baseline: 1.0497x; 1.0080x over previous
//
#include <hip/hip_runtime.h>
#include <hip/hip_bf16.h>

typedef __bf16 bf16x8 __attribute__((ext_vector_type(8)));
typedef __bf16 bf16x4 __attribute__((ext_vector_type(4)));
typedef float fx4 __attribute__((ext_vector_type(4)));
typedef float fx16 __attribute__((ext_vector_type(16)));

#define AS1 __attribute__((address_space(1)))
#define AS3 __attribute__((address_space(3)))

// ---------------------------------------------------------------- cast x -> bf16
__global__ __launch_bounds__(256) void cast_x(const float4* __restrict__ X, __bf16* __restrict__ Xb) {
    int i = blockIdx.x * 256 + threadIdx.x;
    float4 v = X[i];
    bf16x4 o = { (__bf16)v.x, (__bf16)v.y, (__bf16)v.z, (__bf16)v.w };
    *(bf16x4*)(Xb + (size_t)i * 4) = o;
}

// ------------------------------------------------- all 4 weight transposes in one launch
__global__ __launch_bounds__(256) void transpose_all(const float* __restrict__ wq, const float* __restrict__ wk,
                                                     const float* __restrict__ wv, const float* __restrict__ wo,
                                                     __bf16* __restrict__ WqkvT, __bf16* __restrict__ WoT) {
    constexpr int K = 2048;
    __shared__ float t[32][33];
    const int bx = blockIdx.x;
    const float* W; __bf16* Wt; int N, n0;
    if (bx < 64)      { W = wq; Wt = WqkvT;                        N = 2048; n0 = bx * 32; }
    else if (bx < 80) { W = wk; Wt = WqkvT + (size_t)2048 * 2048;  N = 512;  n0 = (bx - 64) * 32; }
    else if (bx < 96) { W = wv; Wt = WqkvT + (size_t)2560 * 2048;  N = 512;  n0 = (bx - 80) * 32; }
    else              { W = wo; Wt = WoT;                          N = 2048; n0 = (bx - 96) * 32; }
    const int tx = threadIdx.x & 31, ty = threadIdx.x >> 5;
    const int k0 = blockIdx.y * 32;
#pragma unroll
    for (int i = 0; i < 4; ++i)
        t[ty + i * 8][tx] = W[(size_t)(k0 + ty + i * 8) * N + n0 + tx];
    __syncthreads();
#pragma unroll
    for (int i = 0; i < 4; ++i)
        Wt[(size_t)(n0 + ty + i * 8) * K + k0 + tx] = (__bf16)t[tx][ty + i * 8];
}

// ------------------------------------------------- QKV GEMM, BN=64, BK=64, fused RoPE/split
__global__ __launch_bounds__(256) void gemm_qkv(const __bf16* __restrict__ A, const __bf16* __restrict__ Bt,
                                                __bf16* __restrict__ Qr, __bf16* __restrict__ Kr,
                                                __bf16* __restrict__ Vt) {
    constexpr int K = 2048;
    __shared__ __align__(16) __bf16 lA[2][128 * 32];
    __shared__ __align__(16) __bf16 lB[2][64 * 32];
    const int tid = threadIdx.x;
    const int wave = tid >> 6, lane = tid & 63;
    const int quad = lane >> 4, l16 = lane & 15;
    const int m0 = blockIdx.x * 128, n0 = blockIdx.y * 64;
    fx4 acc[2][4] = {};

    const __bf16* csrc[6]; __bf16* cdst[6];
#pragma unroll
    for (int it = 0; it < 6; ++it) {
        const int idx = wave * 6 + it;
        const int r4 = lane >> 2, c8 = (lane & 3) * 8;
        if (idx < 16) {
            const int kh = idx & 1, s = idx >> 1;
            csrc[it] = A + (size_t)(m0 + s * 16 + r4) * K + kh * 32 + c8;
            cdst[it] = &lA[kh][s * 512 + lane * 8];
        } else {
            const int b = idx - 16, kh = b & 1, s = b >> 1;
            csrc[it] = Bt + (size_t)(n0 + s * 16 + r4) * K + kh * 32 + c8;
            cdst[it] = &lB[kh][s * 512 + lane * 8];
        }
    }

    for (int k0 = 0; k0 < K; k0 += 64) {
        __syncthreads();
#pragma unroll
        for (int it = 0; it < 6; ++it)
            __builtin_amdgcn_global_load_lds((const AS1 void*)(csrc[it] + k0),
                                             (AS3 void*)cdst[it], 16, 0, 0);
        __builtin_amdgcn_s_waitcnt(0);
        __syncthreads();

#pragma unroll
        for (int kc = 0; kc < 2; ++kc) {
            bf16x8 af[2], bfr[4];
#pragma unroll
            for (int i = 0; i < 2; ++i) af[i] = *(const bf16x8*)&lA[kc][(wave * 32 + i * 16 + l16) * 32 + quad * 8];
#pragma unroll
            for (int j = 0; j < 4; ++j) bfr[j] = *(const bf16x8*)&lB[kc][(j * 16 + l16) * 32 + quad * 8];
#pragma unroll
            for (int i = 0; i < 2; ++i)
#pragma unroll
                for (int j = 0; j < 4; ++j)
                    acc[i][j] = __builtin_amdgcn_mfma_f32_16x16x32_bf16(af[i], bfr[j], acc[i][j], 0, 0, 0);
        }
    }

    const int by = blockIdx.y;
    if (by < 40) {
        const float scale = (by < 32) ? 0.18033688011112042f : 1.0f;   // Q: 0.125*log2(e)
        __bf16* base = (by < 32) ? (Qr + (size_t)by * 2048 * 64)
                                 : (Kr + (size_t)(by - 32) * 2048 * 64);
#pragma unroll
        for (int jj = 0; jj < 2; ++jj) {
            const int dlo = jj * 16 + l16;
            const float inv = __builtin_amdgcn_exp2f(-(float)dlo * 0.41524101186092029f);
#pragma unroll
            for (int i = 0; i < 2; ++i)
#pragma unroll
                for (int r = 0; r < 4; ++r) {
                    const int s = m0 + wave * 32 + i * 16 + quad * 4 + r;
                    float sn, cs;
                    __sincosf((float)s * inv, &sn, &cs);
                    const float lo = acc[i][jj][r], hv = acc[i][jj + 2][r];
                    base[(size_t)s * 64 + dlo]      = (__bf16)((lo * cs - hv * sn) * scale);
                    base[(size_t)s * 64 + dlo + 32] = (__bf16)((hv * cs + lo * sn) * scale);
                }
        }
    } else {
        __bf16* vb = Vt + (size_t)(by - 40) * 64 * 2048;
#pragma unroll
        for (int i = 0; i < 2; ++i)
#pragma unroll
            for (int j = 0; j < 4; ++j) {
                const int d = j * 16 + l16;
                const int s0 = m0 + wave * 32 + i * 16 + quad * 4;
                bf16x4 p;
#pragma unroll
                for (int r = 0; r < 4; ++r) p[r] = (__bf16)acc[i][j][r];
                *(bf16x4*)&vb[(size_t)d * 2048 + s0] = p;
            }
    }
}

// ------------------------------------------------- out-projection GEMM, split-K=2
__global__ __launch_bounds__(256) void gemm_bt_sk(const __bf16* __restrict__ A, const __bf16* __restrict__ Bt,
                                                  float* __restrict__ C0, float* __restrict__ C1,
                                                  int M, int N, int K) {
    __shared__ __align__(16) __bf16 lA[128 * 32];
    __shared__ __align__(16) __bf16 lB[128 * 32];
    const int tid = threadIdx.x;
    const int wave = tid >> 6, lane = tid & 63;
    const int quad = lane >> 4, l16 = lane & 15;
    const int m0 = blockIdx.x * 128, n0 = blockIdx.y * 128;
    const int kz = blockIdx.z;
    const int kbeg = kz * (K >> 1), kend = kbeg + (K >> 1);
    float* C = kz ? C1 : C0;
    const int wm = (wave >> 1) * 64, wn = (wave & 1) * 64;
    fx4 acc[4][4] = {};

    const int st0 = wave * 1024;
    const int st1 = 4096 + wave * 1024;
    const int r0 = (st0 + lane * 16) >> 6, c0 = ((st0 + lane * 16) & 63) >> 1;
    const int r1 = (st1 + lane * 16) >> 6, c1 = ((st1 + lane * 16) & 63) >> 1;

    for (int k0 = kbeg; k0 < kend; k0 += 32) {
        __syncthreads();
        __builtin_amdgcn_global_load_lds((const AS1 void*)(A + (size_t)(m0 + r0) * K + k0 + c0),
                                         (AS3 void*)(lA + (st0 >> 1)), 16, 0, 0);
        __builtin_amdgcn_global_load_lds((const AS1 void*)(A + (size_t)(m0 + r1) * K + k0 + c1),
                                         (AS3 void*)(lA + (st1 >> 1)), 16, 0, 0);
        __builtin_amdgcn_global_load_lds((const AS1 void*)(Bt + (size_t)(n0 + r0) * K + k0 + c0),
                                         (AS3 void*)(lB + (st0 >> 1)), 16, 0, 0);
        __builtin_amdgcn_global_load_lds((const AS1 void*)(Bt + (size_t)(n0 + r1) * K + k0 + c1),
                                         (AS3 void*)(lB + (st1 >> 1)), 16, 0, 0);
        __builtin_amdgcn_s_waitcnt(0);
        __syncthreads();

        bf16x8 af[4], bfr[4];
#pragma unroll
        for (int i = 0; i < 4; ++i) af[i] = *(const bf16x8*)&lA[(wm + i * 16 + l16) * 32 + quad * 8];
#pragma unroll
        for (int j = 0; j < 4; ++j) bfr[j] = *(const bf16x8*)&lB[(wn + j * 16 + l16) * 32 + quad * 8];
#pragma unroll
        for (int i = 0; i < 4; ++i)
#pragma unroll
            for (int j = 0; j < 4; ++j)
                acc[i][j] = __builtin_amdgcn_mfma_f32_16x16x32_bf16(af[i], bfr[j], acc[i][j], 0, 0, 0);
    }
#pragma unroll
    for (int i = 0; i < 4; ++i)
#pragma unroll
        for (int j = 0; j < 4; ++j) {
            const int row = m0 + wm + i * 16 + quad * 4;
            const int col = n0 + wn + j * 16 + l16;
#pragma unroll
            for (int r = 0; r < 4; ++r)
                C[(size_t)(row + r) * N + col] = acc[i][j][r];
        }
}

// ------------------------------------------------- out += partial (deterministic split-K reduce)
__global__ __launch_bounds__(256) void reduce_add(float4* __restrict__ out, const float4* __restrict__ p) {
    const int i = blockIdx.x * 256 + threadIdx.x;
    float4 a = out[i];
    const float4 b = p[i];
    a.x += b.x; a.y += b.y; a.z += b.z; a.w += b.w;
    out[i] = a;
}

// ------------------------------------------------- flash attention: no-P-LDS + 8-wave split-K + LDS dbuf
// grid (16 q-tiles of 128, 32 heads), 512 thr = 8 waves. Waves 0-3 even key-tiles, 4-7 odd,
// private K/V buffers per group, DOUBLE-BUFFERED: one barrier per iteration; iter t computes
// on buf[t&1] while staging tile t+1 into buf[(t+1)&1] (regs prefetched at t-1, full iter of
// vmcnt slack). PV B-operand packed straight from exp2'd score regs (permuted-V, R6).
// Fixed-max softmax -> cross-group combine via plain adds through LDS (overlaid on smem[0]).
__global__ __launch_bounds__(512, 4) void flash_attn(const __bf16* __restrict__ Qr, const __bf16* __restrict__ Kr,
                                                     const __bf16* __restrict__ Vt, __bf16* __restrict__ O) {
    constexpr int S = 2048;
    __shared__ __align__(16) __bf16 smem[2][4 * 64 * 72];   // 73728 B, 2 buffers
    const int qt = blockIdx.x, h = blockIdx.y, kvh = h >> 2;
    const int tid = threadIdx.x, wave = tid >> 6, lane = tid & 63;
    const int grp = wave >> 2, w4 = wave & 3;
    const int l32 = lane & 31, hi = lane >> 5;
    const int goff = grp * 2 * 4608;                        // group's K/V region inside a buffer

    const int qrow = qt * 128 + w4 * 32 + l32;
    const __bf16* qptr = Qr + ((size_t)h * S + qrow) * 64;
    bf16x8 qf[4];
#pragma unroll
    for (int kc = 0; kc < 4; ++kc) qf[kc] = *(const bf16x8*)(qptr + kc * 16 + hi * 8);

    const __bf16* Kbase = Kr + (size_t)kvh * S * 64;
    const __bf16* Vbase = Vt + (size_t)kvh * 64 * S;

    const int gtid = tid & 255;
    const int krow = gtid >> 3;                 // 0..31
    const int kcol = (gtid & 7) * 8;
    const int vslot = (kcol & 48) | ((kcol & 8) >> 1);   // permuted dest of keys [kcol, kcol+4)

    // prefetch tile 0 of this group (kt = grp)
    bf16x8 kreg0 = *(const bf16x8*)(Kbase + (size_t)(grp * 64 + krow) * 64 + kcol);
    bf16x8 kreg1 = *(const bf16x8*)(Kbase + (size_t)(grp * 64 + 32 + krow) * 64 + kcol);
    bf16x8 vreg0 = *(const bf16x8*)(Vbase + (size_t)krow * S + grp * 64 + kcol);
    bf16x8 vreg1 = *(const bf16x8*)(Vbase + (size_t)(32 + krow) * S + grp * 64 + kcol);

    fx16 ov0, ov1;
#pragma unroll
    for (int i = 0; i < 16; ++i) { ov0[i] = 0.f; ov1[i] = 0.f; }
    float l_acc = 0.f;

    // stage tile 0 into buf 0, then prefetch tile 1 (kt = 2 + grp)
    {
        __bf16* nK = &smem[0][goff];
        __bf16* nV = nK + 4608;
        *(bf16x8*)&nK[krow * 72 + kcol] = kreg0;
        *(bf16x8*)&nK[(32 + krow) * 72 + kcol] = kreg1;
        bf16x4 v0lo = { vreg0[0], vreg0[1], vreg0[2], vreg0[3] };
        bf16x4 v0hi = { vreg0[4], vreg0[5], vreg0[6], vreg0[7] };
        bf16x4 v1lo = { vreg1[0], vreg1[1], vreg1[2], vreg1[3] };
        bf16x4 v1hi = { vreg1[4], vreg1[5], vreg1[6], vreg1[7] };
        *(bf16x4*)&nV[krow * 72 + vslot]            = v0lo;
        *(bf16x4*)&nV[krow * 72 + vslot + 8]        = v0hi;
        *(bf16x4*)&nV[(32 + krow) * 72 + vslot]     = v1lo;
        *(bf16x4*)&nV[(32 + krow) * 72 + vslot + 8] = v1hi;
        const int kt1 = 2 + grp;
        kreg0 = *(const bf16x8*)(Kbase + (size_t)(kt1 * 64 + krow) * 64 + kcol);
        kreg1 = *(const bf16x8*)(Kbase + (size_t)(kt1 * 64 + 32 + krow) * 64 + kcol);
        vreg0 = *(const bf16x8*)(Vbase + (size_t)krow * S + kt1 * 64 + kcol);
        vreg1 = *(const bf16x8*)(Vbase + (size_t)(32 + krow) * S + kt1 * 64 + kcol);
    }
    __syncthreads();

    for (int it = 0; it < 16; ++it) {
        __bf16* lKg = &smem[it & 1][goff];
        __bf16* lVg = lKg + 4608;

        // stage tile it+1 into the other buffer; prefetch tile it+2
        if (it + 1 < 16) {
            __bf16* nK = &smem[(it + 1) & 1][goff];
            __bf16* nV = nK + 4608;
            *(bf16x8*)&nK[krow * 72 + kcol] = kreg0;
            *(bf16x8*)&nK[(32 + krow) * 72 + kcol] = kreg1;
            bf16x4 v0lo = { vreg0[0], vreg0[1], vreg0[2], vreg0[3] };
            bf16x4 v0hi = { vreg0[4], vreg0[5], vreg0[6], vreg0[7] };
            bf16x4 v1lo = { vreg1[0], vreg1[1], vreg1[2], vreg1[3] };
            bf16x4 v1hi = { vreg1[4], vreg1[5], vreg1[6], vreg1[7] };
            *(bf16x4*)&nV[krow * 72 + vslot]            = v0lo;
            *(bf16x4*)&nV[krow * 72 + vslot + 8]        = v0hi;
            *(bf16x4*)&nV[(32 + krow) * 72 + vslot]     = v1lo;
            *(bf16x4*)&nV[(32 + krow) * 72 + vslot + 8] = v1hi;
            const int it2 = (it + 2 < 16) ? it + 2 : 15;   // clamped (redundant reload ok)
            const int ktn = it2 * 2 + grp;
            kreg0 = *(const bf16x8*)(Kbase + (size_t)(ktn * 64 + krow) * 64 + kcol);
            kreg1 = *(const bf16x8*)(Kbase + (size_t)(ktn * 64 + 32 + krow) * 64 + kcol);
            vreg0 = *(const bf16x8*)(Vbase + (size_t)krow * S + ktn * 64 + kcol);
            vreg1 = *(const bf16x8*)(Vbase + (size_t)(32 + krow) * S + ktn * 64 + kcol);
        }

        // S^T = K . Q^T  (k-chunks of 16 d)
        fx16 sc0, sc1;
#pragma unroll
        for (int i = 0; i < 16; ++i) { sc0[i] = 0.f; sc1[i] = 0.f; }
#pragma unroll
        for (int kc = 0; kc < 4; ++kc) {
            const bf16x8 a0 = *(const bf16x8*)&lKg[l32 * 72 + kc * 16 + hi * 8];
            const bf16x8 a1 = *(const bf16x8*)&lKg[(32 + l32) * 72 + kc * 16 + hi * 8];
            sc0 = __builtin_amdgcn_mfma_f32_32x32x16_bf16(a0, qf[kc], sc0, 0, 0, 0);
            sc1 = __builtin_amdgcn_mfma_f32_32x32x16_bf16(a1, qf[kc], sc1, 0, 0, 0);
        }

        // fixed-max softmax (p = exp2(s), Q pre-scaled) fused straight into PV
#pragma unroll
        for (int h2 = 0; h2 < 2; ++h2) {
#pragma unroll
            for (int c = 0; c < 2; ++c) {
                bf16x8 pb;
#pragma unroll
                for (int j = 0; j < 8; ++j) {
                    const float sv = h2 ? sc1[c * 8 + j] : sc0[c * 8 + j];
                    const float p = __builtin_amdgcn_exp2f(sv);
                    l_acc += p;
                    pb[j] = (__bf16)p;
                }
                const int kcv = h2 * 2 + c;
                const bf16x8 va0 = *(const bf16x8*)&lVg[l32 * 72 + kcv * 16 + hi * 8];
                const bf16x8 va1 = *(const bf16x8*)&lVg[(32 + l32) * 72 + kcv * 16 + hi * 8];
                ov0 = __builtin_amdgcn_mfma_f32_32x32x16_bf16(va0, pb, ov0, 0, 0, 0);
                ov1 = __builtin_amdgcn_mfma_f32_32x32x16_bf16(va1, pb, ov1, 0, 0, 0);
            }
        }
        __syncthreads();
    }

    // per-wave l over this group's keys (partner lane^32 holds complement)
    const float l_pair = l_acc + __shfl_xor(l_acc, 32, 64);

    // cross-group combine, overlaid on smem[0] (36864 B >= 32768 + 512). Loop's final
    // barrier already ordered all tile reads before these writes.
    fx4* lO = (fx4*)&smem[0][0];                 // [8 chunks][4 w4][64 lanes]
    float* lL = (float*)(&smem[0][0] + 16384);   // byte 32768
    if (grp == 1) {
#pragma unroll
        for (int ic = 0; ic < 4; ++ic) {
            fx4 c0, c1;
#pragma unroll
            for (int r = 0; r < 4; ++r) { c0[r] = ov0[ic * 4 + r]; c1[r] = ov1[ic * 4 + r]; }
            lO[(ic * 4 + w4) * 64 + lane] = c0;
            lO[((ic + 4) * 4 + w4) * 64 + lane] = c1;
        }
        if (hi == 0) lL[w4 * 32 + l32] = l_pair;
    }
    __syncthreads();
    if (grp == 0) {
#pragma unroll
        for (int ic = 0; ic < 4; ++ic) {
            const fx4 c0 = lO[(ic * 4 + w4) * 64 + lane];
            const fx4 c1 = lO[((ic + 4) * 4 + w4) * 64 + lane];
#pragma unroll
            for (int r = 0; r < 4; ++r) { ov0[ic * 4 + r] += c0[r]; ov1[ic * 4 + r] += c1[r]; }
        }
        const float inv_l = 1.0f / (l_pair + lL[w4 * 32 + l32]);
#pragma unroll
        for (int dt = 0; dt < 2; ++dt)
#pragma unroll
            for (int rg2 = 0; rg2 < 4; ++rg2) {
                bf16x4 o4;
#pragma unroll
                for (int r = 0; r < 4; ++r)
                    o4[r] = (__bf16)((dt ? ov1[rg2 * 4 + r] : ov0[rg2 * 4 + r]) * inv_l);
                const int col = h * 64 + dt * 32 + rg2 * 8 + hi * 4;
                *(bf16x4*)(O + (size_t)qrow * 2048 + col) = o4;
            }
    }
}

// ----------------------------------------------------------------------------
extern "C" void kernel_launch(void* const* d_in, const int* in_sizes, int n_in,
                              void* d_out, int out_size, void* d_ws, size_t ws_size,
                              hipStream_t stream) {
    const float* x  = (const float*)d_in[0];
    const float* wq = (const float*)d_in[1];
    const float* wk = (const float*)d_in[2];
    const float* wv = (const float*)d_in[3];
    const float* wo = (const float*)d_in[4];
    float* out = (float*)d_out;
    char* ws = (char*)d_ws;

    __bf16* Xb    = (__bf16*)ws;                        // [0, 8M)
    __bf16* WqkvT = (__bf16*)(ws + ((size_t)8 << 20));  // [8M, 20M)  3072 x 2048
    __bf16* WoT   = (__bf16*)(ws + ((size_t)20 << 20)); // [20M, 28M) 2048 x 2048
    __bf16* Qr    = (__bf16*)(ws + ((size_t)28 << 20)); // [28M, 36M) 32 x 2048 x 64
    __bf16* Kr    = (__bf16*)(ws + ((size_t)36 << 20)); // [36M, 38M)  8 x 2048 x 64
    __bf16* Vt    = (__bf16*)(ws + ((size_t)38 << 20)); // [38M, 40M)  8 x 64 x 2048
    __bf16* Ob    = (__bf16*)(ws + ((size_t)40 << 20)); // [40M, 48M) 2048 x 2048
    float*  Cp    = (float*)ws;                         // [0, 16.8M) split-K partial (Xb/WqkvT dead)

    cast_x<<<4096, 256, 0, stream>>>((const float4*)x, Xb);
    transpose_all<<<dim3(160, 64), 256, 0, stream>>>(wq, wk, wv, wo, WqkvT, WoT);

    gemm_qkv<<<dim3(16, 48), 256, 0, stream>>>(Xb, WqkvT, Qr, Kr, Vt);
    flash_attn<<<dim3(16, 32), 512, 0, stream>>>(Qr, Kr, Vt, Ob);
    gemm_bt_sk<<<dim3(16, 16, 2), 256, 0, stream>>>(Ob, WoT, out, Cp, 2048, 2048, 2048);
    reduce_add<<<4096, 256, 0, stream>>>((float4*)out, (const float4*)Cp);
}